// Round 20
// baseline (119.124 us; speedup 1.0000x reference)
//
#include <hip/hip_runtime.h>
#include <math.h>

// TokenChoiceTopKRouter, round 20: halve memory traffic.
//
// R19 (117 us, -30) validated contiguous 512-B x reads. Remaining traffic
// model: B re-read per wave = 1.07 GB (dominant) + x duplicated 2x = 536 MB
// at ~17 TB/s L2/L3 path. R20: wave = 32 tok x 32 exp (2 A-tiles share every
// B-frag -> B halves); block's 2 eh-waves share ONE x stage (x dup removed).
// Block = 32 tok, 128 thr, LDS 2x16 KB, 4 blocks/CU. T14 stage split:
// global->reg at iter top, ds_write at bottom, one __syncthreads (drain
// covered by full-chunk latency). Race ledger: compute(c) ds_reads sealed by
// per-substep lgkmcnt(0) before barrier(c); stage(c+1) targets the other
// buffer only. Proven numerics (bf16 hi/lo 3-pass, absmax 50) + epilogue.

constexpr int DIM = 4096;
constexpr int NE  = 64;
constexpr int NCH = 32;                          // 128-k chunks
constexpr size_t WSB_BYTES = 1048576;            // packed B stream (1 MB)

typedef __attribute__((ext_vector_type(8))) short bf16x8;
typedef __attribute__((ext_vector_type(4))) float f32x4;

__device__ __forceinline__ f32x4 dsr_f4(const char* p) {
  f32x4 r;
  asm volatile("ds_read_b128 %0, %1"
               : "=v"(r)
               : "v"((const __attribute__((address_space(3))) char*)p));
  return r;
}
__device__ __forceinline__ void dsw_f4(char* p, f32x4 v) {
  asm volatile("ds_write_b128 %0, %1"
               :
               : "v"((__attribute__((address_space(3))) char*)p), "v"(v)
               : "memory");
}

// ---------- k1: pack w into hi/lo B-fragment stream (R6/R10-proven) ---------
// 16B-unit u = sl*512 + f*64 + lane (sl = 32k step 0..127, f = et*2 + hl).
// Content: e = et*16 + (lane&15), k = sl*32 + 8*(lane>>4) (+j), hi/lo bf16.
__global__ void pack_w(const float* __restrict__ w, ushort* __restrict__ wsB) {
  const int u  = blockIdx.x * 256 + threadIdx.x;   // 65536 units
  const int l  = u & 63;
  const int f  = (u >> 6) & 7;
  const int sl = u >> 9;                           // 0..127
  const int et = f >> 1, hl = f & 1;
  const int e  = et * 16 + (l & 15);
  const int k  = sl * 32 + 8 * (l >> 4);
  const float* src = w + (size_t)e * DIM + k;
  ushort v[8];
#pragma unroll
  for (int j = 0; j < 8; ++j) {
    float xv = src[j];
    unsigned xb = __float_as_uint(xv);
    unsigned hb = xb & 0xffff0000u;                // exact hi (truncation)
    if (hl == 0) {
      v[j] = (ushort)(hb >> 16);
    } else {
      float lf = xv - __uint_as_float(hb);
      unsigned lb = __float_as_uint(lf);
      lb = lb + 0x7fffu + ((lb >> 16) & 1u);       // RNE to bf16
      v[j] = (ushort)(lb >> 16);
    }
  }
  ushort* d = wsB + (size_t)u * 8;
#pragma unroll
  for (int j = 0; j < 8; ++j) d[j] = v[j];
}

// ---------- shared helper: two f32x4 -> hi/lo bf16x8 ----------
__device__ __forceinline__ void split8v(const f32x4& a0, const f32x4& a1,
                                        bf16x8& ahi, bf16x8& alo) {
#pragma unroll
  for (int j = 0; j < 8; ++j) {
    float av = (j < 4) ? a0[j] : a1[j - 4];
    unsigned xb = __float_as_uint(av);
    unsigned hb = xb & 0xffff0000u;
    float lf = av - __uint_as_float(hb);
    unsigned lb = __float_as_uint(lf);
    lb = lb + 0x7fffu + ((lb >> 16) & 1u);
    ahi[j] = (short)(hb >> 16);
    alo[j] = (short)(lb >> 16);
  }
}

// ---------- fused main kernel ----------
// 512 blocks x 128 thr (2 waves = eh 0/1), 4 blocks/CU (8 waves/CU).
// Wave: 32 tok x 32 exp x full K; 32 chunks of 128 k (4 x 32-k sub-steps).
// Shared x stage: 2 bufs x 16 KB at (c&1)*16384:
//   [ss(4) x 4096][row(32) x 128][unit(8) x 16, swizzled u^(row&7)]
// Staged cooperatively (16 instrs/block, each 2 rows x 512 B CONTIG).
// B direct-global lane-major (each frag reused by both A-tiles).
__global__ __launch_bounds__(128, 2)
void router_fused(const float* __restrict__ x, const char* __restrict__ wsB,
                  const float* __restrict__ bias,
                  float* __restrict__ out_scores, float* __restrict__ out_idx,
                  float* __restrict__ wsH) {
  __shared__ char lds[32768];
  const int tid  = threadIdx.x;        // 0..127
  const int lane = tid & 63;
  const int eh   = tid >> 6;           // expert half 0..1
  const int col  = lane & 15;
  const int kq   = lane >> 4;
  const int tok0 = blockIdx.x * 32;

  // staging map: unit u = i*128 + tid (i=0..7): row = (tid>>5) + 4*i,
  // j = tid&31. Global: 2 rows x 512 B contiguous per wave-instruction.
  // LDS: ss=j>>3, uu=j&7 -> ss*4096 + row*128 + (uu^(row&7))*16.
  const int srow = tid >> 5;           // 0..3
  const int sj   = tid & 31;
  const int sss  = sj >> 3;
  const int suu  = sj & 7;
  const float* gx = x + (size_t)(tok0 + srow) * DIM + sj * 4;  // +4i*DIM +c*128
  int ldst[8];
#pragma unroll
  for (int i = 0; i < 8; ++i) {
    int row = srow + 4 * i;
    ldst[i] = sss * 4096 + row * 128 + ((suu ^ (row & 7)) * 16);
  }

  // B source: unit (c*4+s4)*512 + (eh*4+f)*64 + lane
  const bf16x8* bpe = (const bf16x8*)wsB + (size_t)eh * 4 * 64 + lane;

  f32x4 acc[4];                        // [tile(2)][et2(2)]
#pragma unroll
  for (int i = 0; i < 4; ++i) acc[i] = (f32x4){0.f, 0.f, 0.f, 0.f};

  // prologue: stage chunk 0
  f32x4 sx[8];
#pragma unroll
  for (int i = 0; i < 8; ++i)
    sx[i] = *(const f32x4*)(gx + (size_t)(4 * i) * DIM);
#pragma unroll
  for (int i = 0; i < 8; ++i) dsw_f4(lds + ldst[i], sx[i]);
  __syncthreads();

  const int am = col & 7;              // (16+col)&7 == col&7: same swizzle key
  const int ua = (kq * 2 + 0) ^ am;
  const int ub = (kq * 2 + 1) ^ am;

#pragma unroll 1
  for (int c = 0; c < NCH; ++c) {
    char* bq  = lds + (c & 1) * 16384;
    char* bqn = lds + ((c + 1) & 1) * 16384;

    // 1. issue chunk c+1 x loads early (T14: land under this chunk's compute)
    if (c + 1 < NCH) {
#pragma unroll
      for (int i = 0; i < 8; ++i)
        sx[i] = *(const f32x4*)(gx + (size_t)(4 * i) * DIM + (c + 1) * 128);
    }
    __builtin_amdgcn_sched_barrier(0);

    // 2. B frags for chunk c (direct global, reused by both A-tiles)
    bf16x8 bf[16];
#pragma unroll
    for (int s4 = 0; s4 < 4; ++s4)
#pragma unroll
      for (int f = 0; f < 4; ++f)
        bf[s4 * 4 + f] = bpe[(size_t)(c * 4 + s4) * 512 + f * 64];

    // 3. compute 4 sub-steps (barrier(c-1) sealed buf bq)
#pragma unroll
    for (int s4 = 0; s4 < 4; ++s4) {
      const char* la = bq + s4 * 4096;
      f32x4 a0 = dsr_f4(la + col * 128 + ua * 16);
      f32x4 a1 = dsr_f4(la + col * 128 + ub * 16);
      f32x4 a2 = dsr_f4(la + (16 + col) * 128 + ua * 16);
      f32x4 a3 = dsr_f4(la + (16 + col) * 128 + ub * 16);
      asm volatile("s_waitcnt lgkmcnt(0)" ::: "memory");
      __builtin_amdgcn_sched_barrier(0);  // rule #18
      bf16x8 ahi, alo;
      split8v(a0, a1, ahi, alo);
      acc[0] = __builtin_amdgcn_mfma_f32_16x16x32_bf16(ahi, bf[s4 * 4 + 0], acc[0], 0, 0, 0);
      acc[0] = __builtin_amdgcn_mfma_f32_16x16x32_bf16(alo, bf[s4 * 4 + 0], acc[0], 0, 0, 0);
      acc[0] = __builtin_amdgcn_mfma_f32_16x16x32_bf16(ahi, bf[s4 * 4 + 1], acc[0], 0, 0, 0);
      acc[1] = __builtin_amdgcn_mfma_f32_16x16x32_bf16(ahi, bf[s4 * 4 + 2], acc[1], 0, 0, 0);
      acc[1] = __builtin_amdgcn_mfma_f32_16x16x32_bf16(alo, bf[s4 * 4 + 2], acc[1], 0, 0, 0);
      acc[1] = __builtin_amdgcn_mfma_f32_16x16x32_bf16(ahi, bf[s4 * 4 + 3], acc[1], 0, 0, 0);
      bf16x8 chi, clo;
      split8v(a2, a3, chi, clo);
      acc[2] = __builtin_amdgcn_mfma_f32_16x16x32_bf16(chi, bf[s4 * 4 + 0], acc[2], 0, 0, 0);
      acc[2] = __builtin_amdgcn_mfma_f32_16x16x32_bf16(clo, bf[s4 * 4 + 0], acc[2], 0, 0, 0);
      acc[2] = __builtin_amdgcn_mfma_f32_16x16x32_bf16(chi, bf[s4 * 4 + 1], acc[2], 0, 0, 0);
      acc[3] = __builtin_amdgcn_mfma_f32_16x16x32_bf16(chi, bf[s4 * 4 + 2], acc[3], 0, 0, 0);
      acc[3] = __builtin_amdgcn_mfma_f32_16x16x32_bf16(clo, bf[s4 * 4 + 2], acc[3], 0, 0, 0);
      acc[3] = __builtin_amdgcn_mfma_f32_16x16x32_bf16(chi, bf[s4 * 4 + 3], acc[3], 0, 0, 0);
    }

    // 4. write chunk c+1 into the other buffer (compiler waits sx's vmcnt)
    if (c + 1 < NCH) {
#pragma unroll
      for (int i = 0; i < 8; ++i) dsw_f4(bqn + ldst[i], sx[i]);
    }
    __syncthreads();   // seals: my reads of bq done; c+1 writes visible
  }

  // ---- epilogue: full-K logits, 32 tok x 32 exp per wave ----
  float* logits = (float*)lds;             // 8 KB (32 x 64)
  float* hist   = (float*)(lds + 8192);    // 256 B
  if (tid < 64) hist[tid] = 0.f;
  // D layout (m89/R6-verified): e-col = et*16+col, token-row = 4*kq+r
#pragma unroll
  for (int tile = 0; tile < 2; ++tile)
#pragma unroll
    for (int et2 = 0; et2 < 2; ++et2)
#pragma unroll
      for (int rr = 0; rr < 4; ++rr) {
        int t = tile * 16 + 4 * kq + rr;
        int e = eh * 32 + et2 * 16 + col;
        logits[t * 64 + ((e + t) & 63)] = acc[tile * 2 + et2][rr];
      }
  __syncthreads();

  // ---- sigmoid + biased top-8 + normalize + LDS hist (proven tail) ----
  if (tid < 32) {
    const int t = tid, gt = tok0 + t;
    float key[8], sv[8];
    int   idx[8];
#pragma unroll
    for (int j = 0; j < 8; ++j) { key[j] = -1e30f; sv[j] = 0.f; idx[j] = 0; }

    for (int e = 0; e < NE; ++e) {
      float l = logits[t * 64 + ((e + t) & 63)];
      float s = 1.0f / (1.0f + expf(-l));
      float k = s + bias[e];
      // bubble-insert; strict > keeps lower index on ties (lax.top_k order)
      float ck = k, cv = s; int ci = e;
#pragma unroll
      for (int j = 0; j < 8; ++j) {
        bool g = ck > key[j];
        float tk = key[j], tv = sv[j]; int ti = idx[j];
        key[j] = g ? ck : tk; sv[j] = g ? cv : tv; idx[j] = g ? ci : ti;
        ck = g ? tk : ck;     cv = g ? tv : cv;    ci = g ? ti : ci;
      }
    }

    float sum = 1e-20f;
#pragma unroll
    for (int j = 0; j < 8; ++j) sum += sv[j];
    float inv = 1.0f / sum;
#pragma unroll
    for (int j = 0; j < 8; ++j) {
      out_scores[gt * 8 + j] = sv[j] * inv;
      out_idx[gt * 8 + j]    = (float)idx[j];
      atomicAdd(&hist[idx[j]], 1.0f);      // LDS atomic
    }
  }
  __syncthreads();
  if (tid < 64) wsH[(size_t)blockIdx.x * NE + tid] = hist[tid];
}

// ---------- k5: reduce per-block histograms (64 blocks, parallel) ----------
__global__ __launch_bounds__(64)
void router_k5(const float* __restrict__ wsH, float* __restrict__ counts,
               int nblk) {
  const int e = blockIdx.x;               // expert
  const int i = threadIdx.x;              // 0..63
  float s = 0.f;
  for (int b = i; b < nblk; b += 64) s += wsH[(size_t)b * NE + e];
#pragma unroll
  for (int off = 32; off >= 1; off >>= 1) s += __shfl_down(s, off, 64);
  if (i == 0) counts[e] = s;
}

// ---------- helper kept for fallbacks ----------
__device__ __forceinline__ void split8(const float4& a0, const float4& a1,
                                       bf16x8& ahi, bf16x8& alo) {
  float av[8] = {a0.x, a0.y, a0.z, a0.w, a1.x, a1.y, a1.z, a1.w};
#pragma unroll
  for (int j = 0; j < 8; ++j) {
    unsigned xb = __float_as_uint(av[j]);
    unsigned hb = xb & 0xffff0000u;
    float lf = av[j] - __uint_as_float(hb);
    unsigned lb = __float_as_uint(lf);
    lb = lb + 0x7fffu + ((lb >> 16) & 1u);
    ahi[j] = (short)(hb >> 16);
    alo[j] = (short)(lb >> 16);
  }
}

// ---------- R6 proven mid-fallback (ws >= 1 MB): direct B-stream MFMA ------
__global__ __launch_bounds__(512, 2)
void router_mfma(const float* __restrict__ x, const ushort* __restrict__ ws,
                 const float* __restrict__ bias,
                 float* __restrict__ out_scores, float* __restrict__ out_idx,
                 float* __restrict__ counts) {
  __shared__ float logits[64 * 64];
  const int tid  = threadIdx.x;
  const int lane = tid & 63;
  const int wv   = tid >> 6;
  const int wt   = wv & 3;
  const int wk   = wv >> 2;
  const int tok0 = blockIdx.x * 64;
  const int col  = lane & 15;
  const int kq   = lane >> 4;
  const float* xrow = x + (size_t)(tok0 + wt * 16 + col) * DIM + wk * 2048 + 8 * kq;
  const ushort* wsl = ws + (size_t)lane * 8;
  f32x4 acc[4];
#pragma unroll
  for (int et = 0; et < 4; ++et) acc[et] = (f32x4){0.f, 0.f, 0.f, 0.f};
  const int s0 = wk * 64;
  float4 a0c = *(const float4*)(xrow + 0);
  float4 a1c = *(const float4*)(xrow + 4);
  bf16x8 bc[8];
#pragma unroll
  for (int f = 0; f < 8; ++f)
    bc[f] = *(const bf16x8*)(wsl + (size_t)(s0 * 8 + f) * 64 * 8);
#pragma unroll 1
  for (int ls = 0; ls < 64; ls += 2) {
    const int so = s0 + ls + 1;
    float4 a0o = *(const float4*)(xrow + (ls + 1) * 32);
    float4 a1o = *(const float4*)(xrow + (ls + 1) * 32 + 4);
    bf16x8 bo[8];
#pragma unroll
    for (int f = 0; f < 8; ++f)
      bo[f] = *(const bf16x8*)(wsl + (size_t)(so * 8 + f) * 64 * 8);
    {
      bf16x8 ahi, alo;
      split8(a0c, a1c, ahi, alo);
#pragma unroll
      for (int et = 0; et < 4; ++et) {
        acc[et] = __builtin_amdgcn_mfma_f32_16x16x32_bf16(ahi, bc[et * 2 + 0], acc[et], 0, 0, 0);
        acc[et] = __builtin_amdgcn_mfma_f32_16x16x32_bf16(alo, bc[et * 2 + 0], acc[et], 0, 0, 0);
        acc[et] = __builtin_amdgcn_mfma_f32_16x16x32_bf16(ahi, bc[et * 2 + 1], acc[et], 0, 0, 0);
      }
    }
    if (ls + 2 < 64) {
      const int se = s0 + ls + 2;
      a0c = *(const float4*)(xrow + (ls + 2) * 32);
      a1c = *(const float4*)(xrow + (ls + 2) * 32 + 4);
#pragma unroll
      for (int f = 0; f < 8; ++f)
        bc[f] = *(const bf16x8*)(wsl + (size_t)(se * 8 + f) * 64 * 8);
    }
    {
      bf16x8 ahi, alo;
      split8(a0o, a1o, ahi, alo);
#pragma unroll
      for (int et = 0; et < 4; ++et) {
        acc[et] = __builtin_amdgcn_mfma_f32_16x16x32_bf16(ahi, bo[et * 2 + 0], acc[et], 0, 0, 0);
        acc[et] = __builtin_amdgcn_mfma_f32_16x16x32_bf16(alo, bo[et * 2 + 0], acc[et], 0, 0, 0);
        acc[et] = __builtin_amdgcn_mfma_f32_16x16x32_bf16(ahi, bo[et * 2 + 1], acc[et], 0, 0, 0);
      }
    }
  }
  if (wk == 0) {
#pragma unroll
    for (int et = 0; et < 4; ++et)
#pragma unroll
      for (int r = 0; r < 4; ++r) {
        int t = wt * 16 + 4 * kq + r;
        int e = et * 16 + col;
        logits[t * 64 + ((e + t) & 63)] = acc[et][r];
      }
  }
  __syncthreads();
  if (wk == 1) {
#pragma unroll
    for (int et = 0; et < 4; ++et)
#pragma unroll
      for (int r = 0; r < 4; ++r) {
        int t = wt * 16 + 4 * kq + r;
        int e = et * 16 + col;
        logits[t * 64 + ((e + t) & 63)] += acc[et][r];
      }
  }
  __syncthreads();
  if (tid < 64) {
    const int t = tid, gt = tok0 + t;
    float key[8], sv[8]; int idx[8];
#pragma unroll
    for (int j = 0; j < 8; ++j) { key[j] = -1e30f; sv[j] = 0.f; idx[j] = 0; }
    for (int e = 0; e < NE; ++e) {
      float l = logits[t * 64 + ((e + t) & 63)];
      float s = 1.0f / (1.0f + expf(-l));
      float k = s + bias[e];
      float ck = k, cv = s; int ci = e;
#pragma unroll
      for (int j = 0; j < 8; ++j) {
        bool g = ck > key[j];
        float tk = key[j], tv = sv[j]; int ti = idx[j];
        key[j] = g ? ck : tk; sv[j] = g ? cv : tv; idx[j] = g ? ci : ti;
        ck = g ? tk : ck;     cv = g ? tv : cv;    ci = g ? ti : ci;
      }
    }
    float sum = 1e-20f;
#pragma unroll
    for (int j = 0; j < 8; ++j) sum += sv[j];
    float inv = 1.0f / sum;
#pragma unroll
    for (int j = 0; j < 8; ++j) {
      out_scores[gt * 8 + j] = sv[j] * inv;
      out_idx[gt * 8 + j]    = (float)idx[j];
      atomicAdd(&counts[idx[j]], 1.0f);
    }
  }
}

// ---------- R5 proven last-resort fallback (fp32 scalar-w) ----------
constexpr int KSTEP = 32;
constexpr int FNSTEP = DIM / KSTEP;
constexpr int ROWF4 = 9;
constexpr int BUF4  = 64 * ROWF4;

__global__ __launch_bounds__(512, 2)
void router_fallback(const float* __restrict__ x, const float* __restrict__ w,
                     const float* __restrict__ bias,
                     float* __restrict__ out_scores, float* __restrict__ out_idx,
                     float* __restrict__ counts) {
  __shared__ float4 lds4[2 * BUF4];
  float* ldsf = (float*)lds4;
  const int tid  = threadIdx.x;
  const int lane = tid & 63;
  const int eg   = __builtin_amdgcn_readfirstlane(tid >> 6);
  const int tok0 = blockIdx.x * 64;
  const int r0 = tid >> 3, j0 = tid & 7;
  const float* gp = &x[(size_t)(tok0 + r0) * DIM + j0 * 4];
  const int l0 = r0 * ROWF4 + j0;
  float acc[8];
#pragma unroll
  for (int e = 0; e < 8; ++e) acc[e] = 0.f;
  lds4[l0] = *(const float4*)gp;
  __syncthreads();
  const float* wbase = w + (size_t)eg * 8 * DIM;
#pragma unroll 1
  for (int c = 0; c < FNSTEP; ++c) {
    float4 pf;
    if (c + 1 < FNSTEP) pf = *(const float4*)(gp + (c + 1) * KSTEP);
    float xr[KSTEP];
    {
      const float4* xrow = lds4 + (c & 1) * BUF4 + lane * ROWF4;
#pragma unroll
      for (int i = 0; i < 8; ++i) {
        float4 q = xrow[i];
        xr[4 * i + 0] = q.x; xr[4 * i + 1] = q.y;
        xr[4 * i + 2] = q.z; xr[4 * i + 3] = q.w;
      }
    }
#pragma unroll
    for (int e = 0; e < 8; ++e) {
      const float* wr = wbase + e * DIM + c * KSTEP;
#pragma unroll
      for (int k = 0; k < KSTEP; ++k) acc[e] = fmaf(xr[k], wr[k], acc[e]);
    }
    if (c + 1 < FNSTEP) lds4[((c + 1) & 1) * BUF4 + l0] = pf;
    __syncthreads();
  }
#pragma unroll
  for (int j = 0; j < 8; ++j) {
    int e = eg * 8 + j;
    ldsf[lane * 64 + ((e + lane) & 63)] = acc[j];
  }
  __syncthreads();
  if (tid < 64) {
    const int t = tid, gt = tok0 + t;
    float key[8], sv[8]; int idx[8];
#pragma unroll
    for (int j = 0; j < 8; ++j) { key[j] = -1e30f; sv[j] = 0.f; idx[j] = 0; }
    for (int e = 0; e < NE; ++e) {
      float l = ldsf[t * 64 + ((e + t) & 63)];
      float s = 1.0f / (1.0f + expf(-l));
      float k = s + bias[e];
      float ck = k, cv = s; int ci = e;
#pragma unroll
      for (int j = 0; j < 8; ++j) {
        bool g = ck > key[j];
        float tk = key[j], tv = sv[j]; int ti = idx[j];
        key[j] = g ? ck : tk; sv[j] = g ? cv : tv; idx[j] = g ? ci : ti;
        ck = g ? tk : ck;     cv = g ? tv : cv;    ci = g ? ti : ci;
      }
    }
    float sum = 1e-20f;
#pragma unroll
    for (int j = 0; j < 8; ++j) sum += sv[j];
    float inv = 1.0f / sum;
#pragma unroll
    for (int j = 0; j < 8; ++j) {
      out_scores[gt * 8 + j] = sv[j] * inv;
      out_idx[gt * 8 + j]    = (float)idx[j];
      atomicAdd(&counts[idx[j]], 1.0f);
    }
  }
}

extern "C" void kernel_launch(void* const* d_in, const int* in_sizes, int n_in,
                              void* d_out, int out_size, void* d_ws, size_t ws_size,
                              hipStream_t stream) {
  const float* x    = (const float*)d_in[0];
  const float* w    = (const float*)d_in[1];
  const float* bias = (const float*)d_in[2];

  const int ntok = in_sizes[0] / DIM;              // 16384
  float* out        = (float*)d_out;
  float* out_scores = out;
  float* out_idx    = out + ntok * 8;
  float* counts     = out + 2 * ntok * 8;

  hipMemsetAsync(counts, 0, NE * sizeof(float), stream);

  const int    nblk      = ntok / 32;              // 512
  const size_t wsh_bytes = (size_t)nblk * NE * sizeof(float);  // 128 KB
  const size_t need = WSB_BYTES + wsh_bytes;

  if (ws_size >= need && (ntok % 32) == 0) {
    ushort* wsB = (ushort*)d_ws;
    float*  wsH = (float*)((char*)d_ws + WSB_BYTES);
    hipLaunchKernelGGL(pack_w, dim3(256), dim3(256), 0, stream, w, wsB);
    hipLaunchKernelGGL(router_fused, dim3(nblk), dim3(128), 0, stream,
                       x, (const char*)wsB, bias, out_scores, out_idx, wsH);
    hipLaunchKernelGGL(router_k5, dim3(NE), dim3(64), 0, stream,
                       wsH, counts, nblk);
  } else if (ws_size >= WSB_BYTES) {
    ushort* wsB = (ushort*)d_ws;
    hipLaunchKernelGGL(pack_w, dim3(256), dim3(256), 0, stream, w, wsB);
    hipLaunchKernelGGL(router_mfma, dim3(ntok / 64), dim3(512), 0, stream,
                       x, wsB, bias, out_scores, out_idx, counts);
  } else {
    hipLaunchKernelGGL(router_fallback, dim3(ntok / 64), dim3(512), 0, stream,
                       x, w, bias, out_scores, out_idx, counts);
  }
}

// Round 21
// 113.840 us; speedup vs baseline: 1.0464x; 1.0464x over previous
//
#include <hip/hip_runtime.h>
#include <math.h>

// TokenChoiceTopKRouter, round 21: intra-chunk pipelining.
//
// R19->R20: halving L2 traffic was FLAT -> latency-chain-bound, not
// traffic-bound. The chain: per substep a full lgkmcnt(0) drain (~120cy LDS
// round-trip) + un-pipelined B-frag global loads (~200-500cy L2). R21:
// (1) all 16 ds_reads issued at chunk top, counted lgkmcnt(12/8/4/0) per
// substep (T4 on the LDS counter); (2) B-frags double-buffered at substep
// granularity (named regs, rule #20) so substep s+1's loads fly under
// substep s's MFMAs. Stage map, swizzle, race ledger identical to R20.
// Proven numerics (bf16 hi/lo 3-pass, absmax 50) + proven epilogue/k5.

constexpr int DIM = 4096;
constexpr int NE  = 64;
constexpr int NCH = 32;                          // 128-k chunks
constexpr size_t WSB_BYTES = 1048576;            // packed B stream (1 MB)

typedef __attribute__((ext_vector_type(8))) short bf16x8;
typedef __attribute__((ext_vector_type(4))) float f32x4;

__device__ __forceinline__ f32x4 dsr_f4(const char* p) {
  f32x4 r;
  asm volatile("ds_read_b128 %0, %1"
               : "=v"(r)
               : "v"((const __attribute__((address_space(3))) char*)p));
  return r;
}
__device__ __forceinline__ void dsw_f4(char* p, f32x4 v) {
  asm volatile("ds_write_b128 %0, %1"
               :
               : "v"((__attribute__((address_space(3))) char*)p), "v"(v)
               : "memory");
}

// ---------- k1: pack w into hi/lo B-fragment stream (R6/R10-proven) ---------
// 16B-unit u = sl*512 + f*64 + lane (sl = 32k step 0..127, f = et*2 + hl).
// Content: e = et*16 + (lane&15), k = sl*32 + 8*(lane>>4) (+j), hi/lo bf16.
__global__ void pack_w(const float* __restrict__ w, ushort* __restrict__ wsB) {
  const int u  = blockIdx.x * 256 + threadIdx.x;   // 65536 units
  const int l  = u & 63;
  const int f  = (u >> 6) & 7;
  const int sl = u >> 9;                           // 0..127
  const int et = f >> 1, hl = f & 1;
  const int e  = et * 16 + (l & 15);
  const int k  = sl * 32 + 8 * (l >> 4);
  const float* src = w + (size_t)e * DIM + k;
  ushort v[8];
#pragma unroll
  for (int j = 0; j < 8; ++j) {
    float xv = src[j];
    unsigned xb = __float_as_uint(xv);
    unsigned hb = xb & 0xffff0000u;                // exact hi (truncation)
    if (hl == 0) {
      v[j] = (ushort)(hb >> 16);
    } else {
      float lf = xv - __uint_as_float(hb);
      unsigned lb = __float_as_uint(lf);
      lb = lb + 0x7fffu + ((lb >> 16) & 1u);       // RNE to bf16
      v[j] = (ushort)(lb >> 16);
    }
  }
  ushort* d = wsB + (size_t)u * 8;
#pragma unroll
  for (int j = 0; j < 8; ++j) d[j] = v[j];
}

// ---------- shared helper: two f32x4 -> hi/lo bf16x8 ----------
__device__ __forceinline__ void split8v(const f32x4& a0, const f32x4& a1,
                                        bf16x8& ahi, bf16x8& alo) {
#pragma unroll
  for (int j = 0; j < 8; ++j) {
    float av = (j < 4) ? a0[j] : a1[j - 4];
    unsigned xb = __float_as_uint(av);
    unsigned hb = xb & 0xffff0000u;
    float lf = av - __uint_as_float(hb);
    unsigned lb = __float_as_uint(lf);
    lb = lb + 0x7fffu + ((lb >> 16) & 1u);
    ahi[j] = (short)(hb >> 16);
    alo[j] = (short)(lb >> 16);
  }
}

// ---------- fused main kernel ----------
// 512 blocks x 128 thr (2 waves = eh 0/1), 4 blocks/CU.
// Wave: 32 tok x 32 exp x full K; 32 chunks of 128 k (4 x 32-k sub-steps).
// Shared x stage: 2 bufs x 16 KB at (c&1)*16384:
//   [ss(4) x 4096][row(32) x 128][unit(8) x 16, swizzled u^(row&7)]
__global__ __launch_bounds__(128, 2)
void router_fused(const float* __restrict__ x, const char* __restrict__ wsB,
                  const float* __restrict__ bias,
                  float* __restrict__ out_scores, float* __restrict__ out_idx,
                  float* __restrict__ wsH) {
  __shared__ char lds[32768];
  const int tid  = threadIdx.x;        // 0..127
  const int lane = tid & 63;
  const int eh   = tid >> 6;           // expert half 0..1
  const int col  = lane & 15;
  const int kq   = lane >> 4;
  const int tok0 = blockIdx.x * 32;

  // staging map (R20-proven): unit u = i*128 + tid: row = (tid>>5)+4i,
  // j = tid&31; global 2 rows x 512 B contiguous; LDS swizzled u^(row&7).
  const int srow = tid >> 5;
  const int sj   = tid & 31;
  const int sss  = sj >> 3;
  const int suu  = sj & 7;
  const float* gx = x + (size_t)(tok0 + srow) * DIM + sj * 4;
  int ldst[8];
#pragma unroll
  for (int i = 0; i < 8; ++i) {
    int row = srow + 4 * i;
    ldst[i] = sss * 4096 + row * 128 + ((suu ^ (row & 7)) * 16);
  }

  // B source: unit (c*4+s4)*512 + (eh*4+f)*64 + lane
  const bf16x8* bpe = (const bf16x8*)wsB + (size_t)eh * 4 * 64 + lane;

  f32x4 acc[4];                        // [tile(2)][et2(2)]
#pragma unroll
  for (int i = 0; i < 4; ++i) acc[i] = (f32x4){0.f, 0.f, 0.f, 0.f};

  // prologue: stage chunk 0
  f32x4 sx[8];
#pragma unroll
  for (int i = 0; i < 8; ++i)
    sx[i] = *(const f32x4*)(gx + (size_t)(4 * i) * DIM);
#pragma unroll
  for (int i = 0; i < 8; ++i) dsw_f4(lds + ldst[i], sx[i]);
  __syncthreads();

  const int am = col & 7;              // (16+col)&7 == col&7
  const int ua = (kq * 2 + 0) ^ am;
  const int ub = (kq * 2 + 1) ^ am;

#define LOADB(u4, B0, B1, B2, B3)                                            \
  do {                                                                      \
    B0 = bpe[(size_t)(u4) * 512 + 0];                                       \
    B1 = bpe[(size_t)(u4) * 512 + 64];                                      \
    B2 = bpe[(size_t)(u4) * 512 + 128];                                     \
    B3 = bpe[(size_t)(u4) * 512 + 192];                                     \
  } while (0)

#define SUBSTEP(sbase, B0, B1, B2, B3)                                       \
  do {                                                                      \
    bf16x8 ahi, alo, chi, clo;                                              \
    split8v(ar[(sbase) + 0], ar[(sbase) + 1], ahi, alo);                    \
    split8v(ar[(sbase) + 2], ar[(sbase) + 3], chi, clo);                    \
    acc[0] = __builtin_amdgcn_mfma_f32_16x16x32_bf16(ahi, B0, acc[0], 0, 0, 0); \
    acc[0] = __builtin_amdgcn_mfma_f32_16x16x32_bf16(alo, B0, acc[0], 0, 0, 0); \
    acc[0] = __builtin_amdgcn_mfma_f32_16x16x32_bf16(ahi, B1, acc[0], 0, 0, 0); \
    acc[1] = __builtin_amdgcn_mfma_f32_16x16x32_bf16(ahi, B2, acc[1], 0, 0, 0); \
    acc[1] = __builtin_amdgcn_mfma_f32_16x16x32_bf16(alo, B2, acc[1], 0, 0, 0); \
    acc[1] = __builtin_amdgcn_mfma_f32_16x16x32_bf16(ahi, B3, acc[1], 0, 0, 0); \
    acc[2] = __builtin_amdgcn_mfma_f32_16x16x32_bf16(chi, B0, acc[2], 0, 0, 0); \
    acc[2] = __builtin_amdgcn_mfma_f32_16x16x32_bf16(clo, B0, acc[2], 0, 0, 0); \
    acc[2] = __builtin_amdgcn_mfma_f32_16x16x32_bf16(chi, B1, acc[2], 0, 0, 0); \
    acc[3] = __builtin_amdgcn_mfma_f32_16x16x32_bf16(chi, B2, acc[3], 0, 0, 0); \
    acc[3] = __builtin_amdgcn_mfma_f32_16x16x32_bf16(clo, B2, acc[3], 0, 0, 0); \
    acc[3] = __builtin_amdgcn_mfma_f32_16x16x32_bf16(chi, B3, acc[3], 0, 0, 0); \
  } while (0)

  bf16x8 bA0, bA1, bA2, bA3, bB0, bB1, bB2, bB3;

#pragma unroll 1
  for (int c = 0; c < NCH; ++c) {
    char* bq  = lds + (c & 1) * 16384;
    char* bqn = lds + ((c + 1) & 1) * 16384;

    // 1. issue chunk c+1 x loads early (T14)
    if (c + 1 < NCH) {
#pragma unroll
      for (int i = 0; i < 8; ++i)
        sx[i] = *(const f32x4*)(gx + (size_t)(4 * i) * DIM + (c + 1) * 128);
    }
    // 2. issue B frags for substep 0
    LOADB(c * 4 + 0, bA0, bA1, bA2, bA3);
    __builtin_amdgcn_sched_barrier(0);

    // 3. issue ALL 16 ds_reads for this chunk (counted waits below)
    f32x4 ar[16];
#pragma unroll
    for (int s4 = 0; s4 < 4; ++s4) {
      const char* la = bq + s4 * 4096;
      ar[s4 * 4 + 0] = dsr_f4(la + col * 128 + ua * 16);
      ar[s4 * 4 + 1] = dsr_f4(la + col * 128 + ub * 16);
      ar[s4 * 4 + 2] = dsr_f4(la + (16 + col) * 128 + ua * 16);
      ar[s4 * 4 + 3] = dsr_f4(la + (16 + col) * 128 + ub * 16);
    }
    __builtin_amdgcn_sched_barrier(0);

    // substep 0: prefetch B(1), wait first 4 reads only
    LOADB(c * 4 + 1, bB0, bB1, bB2, bB3);
    asm volatile("s_waitcnt lgkmcnt(12)" ::: "memory");
    __builtin_amdgcn_sched_barrier(0);           // rule #18
    SUBSTEP(0, bA0, bA1, bA2, bA3);
    // substep 1: prefetch B(2)
    LOADB(c * 4 + 2, bA0, bA1, bA2, bA3);
    asm volatile("s_waitcnt lgkmcnt(8)" ::: "memory");
    __builtin_amdgcn_sched_barrier(0);
    SUBSTEP(4, bB0, bB1, bB2, bB3);
    // substep 2: prefetch B(3)
    LOADB(c * 4 + 3, bB0, bB1, bB2, bB3);
    asm volatile("s_waitcnt lgkmcnt(4)" ::: "memory");
    __builtin_amdgcn_sched_barrier(0);
    SUBSTEP(8, bA0, bA1, bA2, bA3);
    // substep 3: all reads done
    asm volatile("s_waitcnt lgkmcnt(0)" ::: "memory");
    __builtin_amdgcn_sched_barrier(0);
    SUBSTEP(12, bB0, bB1, bB2, bB3);

    // 4. write chunk c+1 into the other buffer, then barrier
    if (c + 1 < NCH) {
#pragma unroll
      for (int i = 0; i < 8; ++i) dsw_f4(bqn + ldst[i], sx[i]);
    }
    __syncthreads();   // seals reads of bq; makes c+1 writes visible
  }
#undef LOADB
#undef SUBSTEP

  // ---- epilogue: full-K logits, 32 tok x 32 exp per wave (R20-proven) ----
  float* logits = (float*)lds;             // 8 KB (32 x 64)
  float* hist   = (float*)(lds + 8192);    // 256 B
  if (tid < 64) hist[tid] = 0.f;
  // D layout (m89/R6-verified): e-col = et*16+col, token-row = 4*kq+r
#pragma unroll
  for (int tile = 0; tile < 2; ++tile)
#pragma unroll
    for (int et2 = 0; et2 < 2; ++et2)
#pragma unroll
      for (int rr = 0; rr < 4; ++rr) {
        int t = tile * 16 + 4 * kq + rr;
        int e = eh * 32 + et2 * 16 + col;
        logits[t * 64 + ((e + t) & 63)] = acc[tile * 2 + et2][rr];
      }
  __syncthreads();

  // ---- sigmoid + biased top-8 + normalize + LDS hist (proven tail) ----
  if (tid < 32) {
    const int t = tid, gt = tok0 + t;
    float key[8], sv[8];
    int   idx[8];
#pragma unroll
    for (int j = 0; j < 8; ++j) { key[j] = -1e30f; sv[j] = 0.f; idx[j] = 0; }

    for (int e = 0; e < NE; ++e) {
      float l = logits[t * 64 + ((e + t) & 63)];
      float s = 1.0f / (1.0f + expf(-l));
      float k = s + bias[e];
      // bubble-insert; strict > keeps lower index on ties (lax.top_k order)
      float ck = k, cv = s; int ci = e;
#pragma unroll
      for (int j = 0; j < 8; ++j) {
        bool g = ck > key[j];
        float tk = key[j], tv = sv[j]; int ti = idx[j];
        key[j] = g ? ck : tk; sv[j] = g ? cv : tv; idx[j] = g ? ci : ti;
        ck = g ? tk : ck;     cv = g ? tv : cv;    ci = g ? ti : ci;
      }
    }

    float sum = 1e-20f;
#pragma unroll
    for (int j = 0; j < 8; ++j) sum += sv[j];
    float inv = 1.0f / sum;
#pragma unroll
    for (int j = 0; j < 8; ++j) {
      out_scores[gt * 8 + j] = sv[j] * inv;
      out_idx[gt * 8 + j]    = (float)idx[j];
      atomicAdd(&hist[idx[j]], 1.0f);      // LDS atomic
    }
  }
  __syncthreads();
  if (tid < 64) wsH[(size_t)blockIdx.x * NE + tid] = hist[tid];
}

// ---------- k5: reduce per-block histograms (64 blocks, parallel) ----------
__global__ __launch_bounds__(64)
void router_k5(const float* __restrict__ wsH, float* __restrict__ counts,
               int nblk) {
  const int e = blockIdx.x;               // expert
  const int i = threadIdx.x;              // 0..63
  float s = 0.f;
  for (int b = i; b < nblk; b += 64) s += wsH[(size_t)b * NE + e];
#pragma unroll
  for (int off = 32; off >= 1; off >>= 1) s += __shfl_down(s, off, 64);
  if (i == 0) counts[e] = s;
}

// ---------- helper kept for fallbacks ----------
__device__ __forceinline__ void split8(const float4& a0, const float4& a1,
                                       bf16x8& ahi, bf16x8& alo) {
  float av[8] = {a0.x, a0.y, a0.z, a0.w, a1.x, a1.y, a1.z, a1.w};
#pragma unroll
  for (int j = 0; j < 8; ++j) {
    unsigned xb = __float_as_uint(av[j]);
    unsigned hb = xb & 0xffff0000u;
    float lf = av[j] - __uint_as_float(hb);
    unsigned lb = __float_as_uint(lf);
    lb = lb + 0x7fffu + ((lb >> 16) & 1u);
    ahi[j] = (short)(hb >> 16);
    alo[j] = (short)(lb >> 16);
  }
}

// ---------- R6 proven mid-fallback (ws >= 1 MB): direct B-stream MFMA ------
__global__ __launch_bounds__(512, 2)
void router_mfma(const float* __restrict__ x, const ushort* __restrict__ ws,
                 const float* __restrict__ bias,
                 float* __restrict__ out_scores, float* __restrict__ out_idx,
                 float* __restrict__ counts) {
  __shared__ float logits[64 * 64];
  const int tid  = threadIdx.x;
  const int lane = tid & 63;
  const int wv   = tid >> 6;
  const int wt   = wv & 3;
  const int wk   = wv >> 2;
  const int tok0 = blockIdx.x * 64;
  const int col  = lane & 15;
  const int kq   = lane >> 4;
  const float* xrow = x + (size_t)(tok0 + wt * 16 + col) * DIM + wk * 2048 + 8 * kq;
  const ushort* wsl = ws + (size_t)lane * 8;
  f32x4 acc[4];
#pragma unroll
  for (int et = 0; et < 4; ++et) acc[et] = (f32x4){0.f, 0.f, 0.f, 0.f};
  const int s0 = wk * 64;
  float4 a0c = *(const float4*)(xrow + 0);
  float4 a1c = *(const float4*)(xrow + 4);
  bf16x8 bc[8];
#pragma unroll
  for (int f = 0; f < 8; ++f)
    bc[f] = *(const bf16x8*)(wsl + (size_t)(s0 * 8 + f) * 64 * 8);
#pragma unroll 1
  for (int ls = 0; ls < 64; ls += 2) {
    const int so = s0 + ls + 1;
    float4 a0o = *(const float4*)(xrow + (ls + 1) * 32);
    float4 a1o = *(const float4*)(xrow + (ls + 1) * 32 + 4);
    bf16x8 bo[8];
#pragma unroll
    for (int f = 0; f < 8; ++f)
      bo[f] = *(const bf16x8*)(wsl + (size_t)(so * 8 + f) * 64 * 8);
    {
      bf16x8 ahi, alo;
      split8(a0c, a1c, ahi, alo);
#pragma unroll
      for (int et = 0; et < 4; ++et) {
        acc[et] = __builtin_amdgcn_mfma_f32_16x16x32_bf16(ahi, bc[et * 2 + 0], acc[et], 0, 0, 0);
        acc[et] = __builtin_amdgcn_mfma_f32_16x16x32_bf16(alo, bc[et * 2 + 0], acc[et], 0, 0, 0);
        acc[et] = __builtin_amdgcn_mfma_f32_16x16x32_bf16(ahi, bc[et * 2 + 1], acc[et], 0, 0, 0);
      }
    }
    if (ls + 2 < 64) {
      const int se = s0 + ls + 2;
      a0c = *(const float4*)(xrow + (ls + 2) * 32);
      a1c = *(const float4*)(xrow + (ls + 2) * 32 + 4);
#pragma unroll
      for (int f = 0; f < 8; ++f)
        bc[f] = *(const bf16x8*)(wsl + (size_t)(se * 8 + f) * 64 * 8);
    }
    {
      bf16x8 ahi, alo;
      split8(a0o, a1o, ahi, alo);
#pragma unroll
      for (int et = 0; et < 4; ++et) {
        acc[et] = __builtin_amdgcn_mfma_f32_16x16x32_bf16(ahi, bo[et * 2 + 0], acc[et], 0, 0, 0);
        acc[et] = __builtin_amdgcn_mfma_f32_16x16x32_bf16(alo, bo[et * 2 + 0], acc[et], 0, 0, 0);
        acc[et] = __builtin_amdgcn_mfma_f32_16x16x32_bf16(ahi, bo[et * 2 + 1], acc[et], 0, 0, 0);
      }
    }
  }
  if (wk == 0) {
#pragma unroll
    for (int et = 0; et < 4; ++et)
#pragma unroll
      for (int r = 0; r < 4; ++r) {
        int t = wt * 16 + 4 * kq + r;
        int e = et * 16 + col;
        logits[t * 64 + ((e + t) & 63)] = acc[et][r];
      }
  }
  __syncthreads();
  if (wk == 1) {
#pragma unroll
    for (int et = 0; et < 4; ++et)
#pragma unroll
      for (int r = 0; r < 4; ++r) {
        int t = wt * 16 + 4 * kq + r;
        int e = et * 16 + col;
        logits[t * 64 + ((e + t) & 63)] += acc[et][r];
      }
  }
  __syncthreads();
  if (tid < 64) {
    const int t = tid, gt = tok0 + t;
    float key[8], sv[8]; int idx[8];
#pragma unroll
    for (int j = 0; j < 8; ++j) { key[j] = -1e30f; sv[j] = 0.f; idx[j] = 0; }
    for (int e = 0; e < NE; ++e) {
      float l = logits[t * 64 + ((e + t) & 63)];
      float s = 1.0f / (1.0f + expf(-l));
      float k = s + bias[e];
      float ck = k, cv = s; int ci = e;
#pragma unroll
      for (int j = 0; j < 8; ++j) {
        bool g = ck > key[j];
        float tk = key[j], tv = sv[j]; int ti = idx[j];
        key[j] = g ? ck : tk; sv[j] = g ? cv : tv; idx[j] = g ? ci : ti;
        ck = g ? tk : ck;     cv = g ? tv : cv;    ci = g ? ti : ci;
      }
    }
    float sum = 1e-20f;
#pragma unroll
    for (int j = 0; j < 8; ++j) sum += sv[j];
    float inv = 1.0f / sum;
#pragma unroll
    for (int j = 0; j < 8; ++j) {
      out_scores[gt * 8 + j] = sv[j] * inv;
      out_idx[gt * 8 + j]    = (float)idx[j];
      atomicAdd(&counts[idx[j]], 1.0f);
    }
  }
}

// ---------- R5 proven last-resort fallback (fp32 scalar-w) ----------
constexpr int KSTEP = 32;
constexpr int FNSTEP = DIM / KSTEP;
constexpr int ROWF4 = 9;
constexpr int BUF4  = 64 * ROWF4;

__global__ __launch_bounds__(512, 2)
void router_fallback(const float* __restrict__ x, const float* __restrict__ w,
                     const float* __restrict__ bias,
                     float* __restrict__ out_scores, float* __restrict__ out_idx,
                     float* __restrict__ counts) {
  __shared__ float4 lds4[2 * BUF4];
  float* ldsf = (float*)lds4;
  const int tid  = threadIdx.x;
  const int lane = tid & 63;
  const int eg   = __builtin_amdgcn_readfirstlane(tid >> 6);
  const int tok0 = blockIdx.x * 64;
  const int r0 = tid >> 3, j0 = tid & 7;
  const float* gp = &x[(size_t)(tok0 + r0) * DIM + j0 * 4];
  const int l0 = r0 * ROWF4 + j0;
  float acc[8];
#pragma unroll
  for (int e = 0; e < 8; ++e) acc[e] = 0.f;
  lds4[l0] = *(const float4*)gp;
  __syncthreads();
  const float* wbase = w + (size_t)eg * 8 * DIM;
#pragma unroll 1
  for (int c = 0; c < FNSTEP; ++c) {
    float4 pf;
    if (c + 1 < FNSTEP) pf = *(const float4*)(gp + (c + 1) * KSTEP);
    float xr[KSTEP];
    {
      const float4* xrow = lds4 + (c & 1) * BUF4 + lane * ROWF4;
#pragma unroll
      for (int i = 0; i < 8; ++i) {
        float4 q = xrow[i];
        xr[4 * i + 0] = q.x; xr[4 * i + 1] = q.y;
        xr[4 * i + 2] = q.z; xr[4 * i + 3] = q.w;
      }
    }
#pragma unroll
    for (int e = 0; e < 8; ++e) {
      const float* wr = wbase + e * DIM + c * KSTEP;
#pragma unroll
      for (int k = 0; k < KSTEP; ++k) acc[e] = fmaf(xr[k], wr[k], acc[e]);
    }
    if (c + 1 < FNSTEP) lds4[((c + 1) & 1) * BUF4 + l0] = pf;
    __syncthreads();
  }
#pragma unroll
  for (int j = 0; j < 8; ++j) {
    int e = eg * 8 + j;
    ldsf[lane * 64 + ((e + lane) & 63)] = acc[j];
  }
  __syncthreads();
  if (tid < 64) {
    const int t = tid, gt = tok0 + t;
    float key[8], sv[8]; int idx[8];
#pragma unroll
    for (int j = 0; j < 8; ++j) { key[j] = -1e30f; sv[j] = 0.f; idx[j] = 0; }
    for (int e = 0; e < NE; ++e) {
      float l = ldsf[t * 64 + ((e + t) & 63)];
      float s = 1.0f / (1.0f + expf(-l));
      float k = s + bias[e];
      float ck = k, cv = s; int ci = e;
#pragma unroll
      for (int j = 0; j < 8; ++j) {
        bool g = ck > key[j];
        float tk = key[j], tv = sv[j]; int ti = idx[j];
        key[j] = g ? ck : tk; sv[j] = g ? cv : tv; idx[j] = g ? ci : ti;
        ck = g ? tk : ck;     cv = g ? tv : cv;    ci = g ? ti : ci;
      }
    }
    float sum = 1e-20f;
#pragma unroll
    for (int j = 0; j < 8; ++j) sum += sv[j];
    float inv = 1.0f / sum;
#pragma unroll
    for (int j = 0; j < 8; ++j) {
      out_scores[gt * 8 + j] = sv[j] * inv;
      out_idx[gt * 8 + j]    = (float)idx[j];
      atomicAdd(&counts[idx[j]], 1.0f);
    }
  }
}

extern "C" void kernel_launch(void* const* d_in, const int* in_sizes, int n_in,
                              void* d_out, int out_size, void* d_ws, size_t ws_size,
                              hipStream_t stream) {
  const float* x    = (const float*)d_in[0];
  const float* w    = (const float*)d_in[1];
  const float* bias = (const float*)d_in[2];

  const int ntok = in_sizes[0] / DIM;              // 16384
  float* out        = (float*)d_out;
  float* out_scores = out;
  float* out_idx    = out + ntok * 8;
  float* counts     = out + 2 * ntok * 8;

  hipMemsetAsync(counts, 0, NE * sizeof(float), stream);

  const int    nblk      = ntok / 32;              // 512
  const size_t wsh_bytes = (size_t)nblk * NE * sizeof(float);  // 128 KB
  const size_t need = WSB_BYTES + wsh_bytes;

  if (ws_size >= need && (ntok % 32) == 0) {
    ushort* wsB = (ushort*)d_ws;
    float*  wsH = (float*)((char*)d_ws + WSB_BYTES);
    hipLaunchKernelGGL(pack_w, dim3(256), dim3(256), 0, stream, w, wsB);
    hipLaunchKernelGGL(router_fused, dim3(nblk), dim3(128), 0, stream,
                       x, (const char*)wsB, bias, out_scores, out_idx, wsH);
    hipLaunchKernelGGL(router_k5, dim3(NE), dim3(64), 0, stream,
                       wsH, counts, nblk);
  } else if (ws_size >= WSB_BYTES) {
    ushort* wsB = (ushort*)d_ws;
    hipLaunchKernelGGL(pack_w, dim3(256), dim3(256), 0, stream, w, wsB);
    hipLaunchKernelGGL(router_mfma, dim3(ntok / 64), dim3(512), 0, stream,
                       x, wsB, bias, out_scores, out_idx, counts);
  } else {
    hipLaunchKernelGGL(router_fallback, dim3(ntok / 64), dim3(512), 0, stream,
                       x, w, bias, out_scores, out_idx, counts);
  }
}